// Round 6
// baseline (214.544 us; speedup 1.0000x reference)
//
#include <hip/hip_runtime.h>

// LocalPathEncoderRobustAdvancedTemporal — R9: persistent barrier-free streaming GEMM.
// out[b,l,:] = (Σ_f relu(x_f*W1 + b1)) @ W2 + 8*b2   (8x FLOP collapse, exact)
//
// R8 (split) was the first win: 193->185. Window = fill(85) + restores(~30) +
// ours(~70, floor ~30). k2's remaining overheads: (1) 2048-block churn, each
// re-staging 32KB W2^T + barrier for only 64KB of stores; (2) w2t_prep dispatch
// + gap; (3) LDS-transpose epilogue fences (format exonerated by R5/R6 -> dead
// weight). R9:
//  * k2 persistent: grid 1024 = exactly 4 blocks/CU (36KB LDS), stage W2^T
//    ONCE per block (in-kernel f32->bf16, packed ds_write_b32; prep dispatch
//    deleted), one barrier, then 2 chunks x 128 rows with ZERO barriers/fences:
//    feats -> pk-fma -> MFMA -> direct nt f32x4 stores. Waves fully decoupled,
//    streaming stores for their whole life.
//  * chunk-0 feats issued before staging (latency hidden under it).
//  * k1 unchanged (verified). Numerics bit-identical.

#define EPSF 1e-6f
#define LDB 136

typedef __attribute__((ext_vector_type(8))) short bf16x8;
typedef __attribute__((ext_vector_type(4))) float f32x4;
typedef __attribute__((ext_vector_type(2))) float f32x2;

__device__ inline short f2bf(float x) {           // fp32 -> bf16 (RNE)
    unsigned u = __float_as_uint(x);
    return (short)((u + 0x7fffu + ((u >> 16) & 1u)) >> 16);
}

// ---------------- k1: stats + cross features -> feats[2][2048][64][8] ----------------
__launch_bounds__(128)
__global__ void lpe_feats(const int* __restrict__ src_ids,
                          const int* __restrict__ dst_ids,
                          const int* __restrict__ src_nid,
                          const int* __restrict__ dst_nid,
                          const float* __restrict__ t_now,
                          const float* __restrict__ src_t,
                          const float* __restrict__ dst_t,
                          float* __restrict__ fs)
{
    __shared__ int2  s_idt[128];                  // (id, t) per local row
    __shared__ __align__(16) f32x4 s_tab[2][512]; // per (side,id): n,avg,rec,last_t

    const int tid  = threadIdx.x;                 // 0..127
    const int b    = blockIdx.x;                  // one sample per block
    const int side = tid >> 6;
    const int i    = tid & 63;

    // zero n-fields (other fields are n>0-guarded)
    #pragma unroll
    for (int u = tid; u < 1024; u += 128) ((float*)s_tab)[u * 4] = 0.f;

    const float cur = t_now[b];
    const int   s_n = src_nid[b], d_n = dst_nid[b];

    const int*   idp = side ? dst_ids : src_ids;
    const float* tp  = side ? dst_t   : src_t;
    const int   my_id = idp[b * 64 + i];
    const float my_t  = tp [b * 64 + i];
    s_idt[tid] = make_int2(my_id, __float_as_int(my_t));
    __syncthreads();

    // ---- stats: n, tmax, tmin, rank, has-later ----
    int n = 0, rank = 0, later = 0;
    float tmax = -3.4e38f, tmin = 3.4e38f;
    const int sbase = side * 64;
    #pragma unroll 8
    for (int j = 0; j < 64; ++j) {
        const int2 e = s_idt[sbase + j];
        const float tj = __int_as_float(e.y);
        if (e.x == my_id) {
            ++n;
            tmax = fmaxf(tmax, tj);
            tmin = fminf(tmin, tj);
            if (tj < my_t || (tj == my_t && j < i)) ++rank;
            if (j > i) later = 1;
        }
    }
    const float nf    = (float)n;
    const int   split = n >> 1;
    const float avg   = (n > 1) ? (tmax - tmin) / (nf - 1.f) : 0.f;
    if (my_id != 0) {
        s_tab[side][my_id].x = nf;     // benign race: same value from all members
        s_tab[side][my_id].y = avg;
        if (rank == split)             // unique member: sorted(ts)[n//2] == my_t
            s_tab[side][my_id].z = (n >= 4)
                ? (tmax - my_t) / fmaxf(nf - (float)split - 1.f, 1.f) : 0.f;
        if (!later)                    // unique member: last occurrence
            s_tab[side][my_id].w = my_t;
    }
    __syncthreads();

    // ---- cross features: O(1) table reads ----
    const int os = side ^ 1;
    const float rec_m = (my_id != 0) ? s_tab[side][my_id].z : 0.f;
    const f32x4 to = s_tab[os][my_id];
    const float n_o = (my_id != 0) ? to.x : 0.f;
    const bool  hit = n_o > 0.f;
    const float avg_o = hit ? to.y : 0.f;
    const float rec_o = hit ? to.z : 0.f;
    const float lastt = hit ? to.w : 0.f;
    const int other_node = side ? s_n : d_n;
    const float m = (my_id != 0) ? 1.f : 0.f;

    const float rcy_s = cur - my_t;
    const float rcy_o = cur - lastt;
    f32x4 f0, f1;
    f0.x = m * nf;
    f0.y = m * n_o;
    f0.z = m * ((my_id == other_node) ? 1.f : 0.f);
    f0.w = m * (hit ? 1.f : 0.f);
    f1.x = m * (hit ? nf / (n_o + EPSF) : 0.f);
    f1.y = m * ((rcy_s > EPSF) ? rcy_o / (rcy_s + EPSF) : 0.f);
    f1.z = m * ((avg_o > EPSF) ? avg / (avg_o + EPSF) : 0.f);
    f1.w = m * ((rec_o > EPSF) ? rec_m / (rec_o + EPSF) : 0.f);

    const long rowf = (long)side * 131072 + (long)b * 64 + i;   // [side][b][l]
    *(f32x4*)&fs[rowf * 8]     = f0;
    *(f32x4*)&fs[rowf * 8 + 4] = f1;
}

// ---------------- k2: persistent streaming first-layer + GEMM + writer ----------------
__launch_bounds__(256, 4)
__global__ void lpe_gemm(const float* __restrict__ fs,
                         const float* __restrict__ W2,
                         const float* __restrict__ W1,
                         const float* __restrict__ b1,
                         const float* __restrict__ b2,
                         float* __restrict__ out)
{
    __shared__ __align__(16) float s_w1[128], s_b1[128], s_b2[128];
    __shared__ __align__(16) short W2T[128 * LDB];     // W2^T bf16, padded rows

    const int tid  = threadIdx.x;
    const int lane = tid & 63, wv = tid >> 6;
    const int quad = lane >> 4, ln = lane & 15;

    // ---- issue chunk-0 feats loads early (latency hides under staging) ----
    f32x4 fa0[2], fb0[2];
    #pragma unroll
    for (int rg = 0; rg < 2; ++rg) {
        const long rowf = (long)blockIdx.x * 128 + wv * 32 + rg * 16 + ln;
        fa0[rg] = *(const f32x4*)&fs[rowf * 8];
        fb0[rg] = *(const f32x4*)&fs[rowf * 8 + 4];
    }

    // ---- stage W2^T once: convert f32 -> bf16, packed pairs along k ----
    // W2 is [k][n] (128x128). W2T[n][k] with k-pairs packed into one b32 write.
    for (int v = tid; v < 8192; v += 256) {
        const int kp = v >> 7, n = v & 127;            // kp: k-pair 0..63
        const float a = W2[(2 * kp)     * 128 + n];    // coalesced in n across lanes
        const float c = W2[(2 * kp + 1) * 128 + n];
        const unsigned pk = (unsigned)(unsigned short)f2bf(a)
                          | ((unsigned)(unsigned short)f2bf(c) << 16);
        *(unsigned*)&W2T[n * LDB + 2 * kp] = pk;
    }
    if (tid < 128) { s_w1[tid] = W1[tid]; s_b1[tid] = b1[tid]; s_b2[tid] = b2[tid]; }
    __syncthreads();
    // ---- no barriers / no LDS writes from here on: pure streaming ----

    #pragma unroll 2
    for (int ch = 0; ch < 2; ++ch) {
        const long base = (long)(blockIdx.x + ch * 1024) * 128;

        float fxr[2][8];
        if (ch == 0) {
            #pragma unroll
            for (int rg = 0; rg < 2; ++rg) {
                fxr[rg][0] = fa0[rg].x; fxr[rg][1] = fa0[rg].y;
                fxr[rg][2] = fa0[rg].z; fxr[rg][3] = fa0[rg].w;
                fxr[rg][4] = fb0[rg].x; fxr[rg][5] = fb0[rg].y;
                fxr[rg][6] = fb0[rg].z; fxr[rg][7] = fb0[rg].w;
            }
        } else {
            #pragma unroll
            for (int rg = 0; rg < 2; ++rg) {
                const long rowf = base + wv * 32 + rg * 16 + ln;
                const f32x4 a = *(const f32x4*)&fs[rowf * 8];
                const f32x4 c = *(const f32x4*)&fs[rowf * 8 + 4];
                fxr[rg][0] = a.x; fxr[rg][1] = a.y; fxr[rg][2] = a.z; fxr[rg][3] = a.w;
                fxr[rg][4] = c.x; fxr[rg][5] = c.y; fxr[rg][6] = c.z; fxr[rg][7] = c.w;
            }
        }

        // ---- first layer: g = sum_f relu(x_f*W1+b1), bf16 fragments ----
        bf16x8 gf[2][4];                               // [row-tile][k-block]
        #pragma unroll
        for (int kk = 0; kk < 4; ++kk) {
            const int kb = kk * 32 + quad * 8;
            #pragma unroll
            for (int rg = 0; rg < 2; ++rg) {
                #pragma unroll
                for (int u2 = 0; u2 < 4; ++u2) {
                    const f32x2 w  = *(const f32x2*)&s_w1[kb + u2 * 2];
                    const f32x2 bb = *(const f32x2*)&s_b1[kb + u2 * 2];
                    f32x2 sv = {0.f, 0.f};
                    #pragma unroll
                    for (int f = 0; f < 8; ++f) {
                        const f32x2 h = w * fxr[rg][f] + bb;      // v_pk_fma_f32
                        sv += __builtin_elementwise_max(h, (f32x2){0.f, 0.f});
                    }
                    gf[rg][kk][u2 * 2]     = f2bf(sv.x);
                    gf[rg][kk][u2 * 2 + 1] = f2bf(sv.y);
                }
            }
        }

        // ---- GEMM + direct nt stores (format exonerated R5/R6; no fences) ----
        #pragma unroll
        for (int et = 0; et < 8; ++et) {
            bf16x8 af[4];
            #pragma unroll
            for (int kk = 0; kk < 4; ++kk)
                af[kk] = *(const bf16x8*)&W2T[(et * 16 + ln) * LDB + kk * 32 + quad * 8];
            f32x4 acc[2] = {(f32x4){0.f,0.f,0.f,0.f}, (f32x4){0.f,0.f,0.f,0.f}};
            #pragma unroll
            for (int kk = 0; kk < 4; ++kk)
                #pragma unroll
                for (int rg = 0; rg < 2; ++rg)
                    acc[rg] = __builtin_amdgcn_mfma_f32_16x16x32_bf16(af[kk], gf[rg][kk], acc[rg], 0, 0, 0);

            const int e0 = et * 16 + quad * 4;
            const f32x4 badd = *(const f32x4*)&s_b2[e0] * 8.f;
            #pragma unroll
            for (int rg = 0; rg < 2; ++rg) {
                const long rowf = base + wv * 32 + rg * 16 + ln;
                __builtin_nontemporal_store(acc[rg] + badd,
                    (f32x4*)&out[rowf * 128 + e0]);
            }
        }
    }
}

// ---------------- fallback: R7 fused (ws too small) ----------------
__launch_bounds__(256, 2)
__global__ void lpe_fused4(const int* __restrict__ src_ids,
                           const int* __restrict__ dst_ids,
                           const int* __restrict__ src_nid,
                           const int* __restrict__ dst_nid,
                           const float* __restrict__ t_now,
                           const float* __restrict__ src_t,
                           const float* __restrict__ dst_t,
                           const float* __restrict__ W1,
                           const float* __restrict__ b1,
                           const float* __restrict__ W2,
                           const float* __restrict__ b2,
                           float* __restrict__ out)
{
    __shared__ int2  s_idt[128];
    __shared__ __align__(16) f32x4 s_tab[2][512];
    __shared__ float s_feats[128][9];
    __shared__ __align__(16) float s_w1[128], s_b1[128], s_b2[128];
    __shared__ __align__(16) float s_stage[4][32][32];
    __shared__ __align__(16) short W2T[128 * LDB];

    const int tid  = threadIdx.x;
    const int b4   = blockIdx.x * 4;
    const int lane = tid & 63, wv = tid >> 6;
    const int quad = lane >> 4, ln = lane & 15;
    const int side = (tid >> 6) & 1;
    const int i    = tid & 63;

    if (tid < 128) { s_w1[tid] = W1[tid]; s_b1[tid] = b1[tid]; s_b2[tid] = b2[tid]; }
    for (int u = tid; u < 16384; u += 256) {
        const int k = u >> 7, n = u & 127;
        W2T[n * LDB + k] = f2bf(W2[u]);
    }
    const int*   idp = side ? dst_ids : src_ids;
    const float* tp  = side ? dst_t   : src_t;
    int   pf_id = 0; float pf_t = 0.f;
    if (tid < 128) { pf_id = idp[b4 * 64 + i]; pf_t = tp[b4 * 64 + i]; }
    float cur = t_now[b4];
    int   s_n = src_nid[b4], d_n = dst_nid[b4];
    for (int u = tid; u < 1024; u += 256) ((float*)s_tab)[u * 4] = 0.f;
    const long side_stride = 2048L * 64L * 128L;

    for (int s = 0; s < 4; ++s) {
        const int   my_id = pf_id;  const float my_t = pf_t;
        const float curs  = cur;    const int sns = s_n, dns = d_n;
        if (tid < 128) s_idt[tid] = make_int2(my_id, __float_as_int(my_t));
        __syncthreads();

        float nf = 0.f, avg = 0.f;
        if (tid < 128) {
            int n = 0, rank = 0, later = 0;
            float tmax = -3.4e38f, tmin = 3.4e38f;
            const int sbase = side * 64;
            #pragma unroll 8
            for (int j = 0; j < 64; ++j) {
                const int2 e = s_idt[sbase + j];
                const float tj = __int_as_float(e.y);
                if (e.x == my_id) {
                    ++n; tmax = fmaxf(tmax, tj); tmin = fminf(tmin, tj);
                    if (tj < my_t || (tj == my_t && j < i)) ++rank;
                    if (j > i) later = 1;
                }
            }
            nf = (float)n;
            const int split = n >> 1;
            avg = (n > 1) ? (tmax - tmin) / (nf - 1.f) : 0.f;
            if (my_id != 0) {
                s_tab[side][my_id].x = nf;
                s_tab[side][my_id].y = avg;
                if (rank == split)
                    s_tab[side][my_id].z = (n >= 4)
                        ? (tmax - my_t) / fmaxf(nf - (float)split - 1.f, 1.f) : 0.f;
                if (!later) s_tab[side][my_id].w = my_t;
            }
        }
        if (s < 3) {
            if (tid < 128) {
                pf_id = idp[(b4 + s + 1) * 64 + i];
                pf_t  = tp [(b4 + s + 1) * 64 + i];
            }
            cur = t_now[b4 + s + 1];
            s_n = src_nid[b4 + s + 1];
            d_n = dst_nid[b4 + s + 1];
        }
        __syncthreads();

        if (tid < 128) {
            const int os = side ^ 1;
            const float rec_m = (my_id != 0) ? s_tab[side][my_id].z : 0.f;
            const f32x4 to = s_tab[os][my_id];
            const float n_o = (my_id != 0) ? to.x : 0.f;
            const bool  hit = n_o > 0.f;
            const float avg_o = hit ? to.y : 0.f;
            const float rec_o = hit ? to.z : 0.f;
            const float lastt = hit ? to.w : 0.f;
            const int other_node = side ? sns : dns;
            const float m = (my_id != 0) ? 1.f : 0.f;
            const float rcy_s = curs - my_t;
            const float rcy_o = curs - lastt;
            s_feats[tid][0] = m * nf;
            s_feats[tid][1] = m * n_o;
            s_feats[tid][2] = m * ((my_id == other_node) ? 1.f : 0.f);
            s_feats[tid][3] = m * (hit ? 1.f : 0.f);
            s_feats[tid][4] = m * (hit ? nf / (n_o + EPSF) : 0.f);
            s_feats[tid][5] = m * ((rcy_s > EPSF) ? rcy_o / (rcy_s + EPSF) : 0.f);
            s_feats[tid][6] = m * ((avg_o > EPSF) ? avg / (avg_o + EPSF) : 0.f);
            s_feats[tid][7] = m * ((rec_o > EPSF) ? rec_m / (rec_o + EPSF) : 0.f);
        }
        __syncthreads();

        float fxr[2][8];
        #pragma unroll
        for (int rg = 0; rg < 2; ++rg) {
            const int row = wv * 32 + rg * 16 + ln;
            #pragma unroll
            for (int j = 0; j < 8; ++j) fxr[rg][j] = s_feats[row][j];
        }
        if (s < 3)
            for (int u = tid; u < 1024; u += 256) ((float*)s_tab)[u * 4] = 0.f;

        bf16x8 gf[2][4];
        #pragma unroll
        for (int kk = 0; kk < 4; ++kk) {
            const int kb = kk * 32 + quad * 8;
            #pragma unroll
            for (int rg = 0; rg < 2; ++rg) {
                #pragma unroll
                for (int u2 = 0; u2 < 4; ++u2) {
                    const f32x2 w  = *(const f32x2*)&s_w1[kb + u2 * 2];
                    const f32x2 bb = *(const f32x2*)&s_b1[kb + u2 * 2];
                    f32x2 sv = {0.f, 0.f};
                    #pragma unroll
                    for (int f = 0; f < 8; ++f) {
                        const f32x2 h = w * fxr[rg][f] + bb;
                        sv += __builtin_elementwise_max(h, (f32x2){0.f, 0.f});
                    }
                    gf[rg][kk][u2 * 2]     = f2bf(sv.x);
                    gf[rg][kk][u2 * 2 + 1] = f2bf(sv.y);
                }
            }
        }

        float* st = &s_stage[wv][0][0];
        const int sw = ln & 7;
        const long rowbase = (long)(b4 + s) * 64;

        #pragma unroll
        for (int p = 0; p < 4; ++p) {
            const int et0 = 2 * p, et1 = 2 * p + 1;
            bf16x8 afA[4], afB[4];
            #pragma unroll
            for (int kk = 0; kk < 4; ++kk) {
                afA[kk] = *(const bf16x8*)&W2T[(et0 * 16 + ln) * LDB + kk * 32 + quad * 8];
                afB[kk] = *(const bf16x8*)&W2T[(et1 * 16 + ln) * LDB + kk * 32 + quad * 8];
            }
            f32x4 accA[2] = {(f32x4){0.f,0.f,0.f,0.f}, (f32x4){0.f,0.f,0.f,0.f}};
            f32x4 accB[2] = {(f32x4){0.f,0.f,0.f,0.f}, (f32x4){0.f,0.f,0.f,0.f}};
            #pragma unroll
            for (int kk = 0; kk < 4; ++kk)
                #pragma unroll
                for (int rg = 0; rg < 2; ++rg) {
                    accA[rg] = __builtin_amdgcn_mfma_f32_16x16x32_bf16(afA[kk], gf[rg][kk], accA[rg], 0, 0, 0);
                    accB[rg] = __builtin_amdgcn_mfma_f32_16x16x32_bf16(afB[kk], gf[rg][kk], accB[rg], 0, 0, 0);
                }
            const f32x4 bA = *(const f32x4*)&s_b2[et0 * 16 + quad * 4] * 8.f;
            const f32x4 bB = *(const f32x4*)&s_b2[et1 * 16 + quad * 4] * 8.f;

            if (p)
                asm volatile("s_waitcnt lgkmcnt(0)" ::: "memory");
            #pragma unroll
            for (int rg = 0; rg < 2; ++rg) {
                const int row = rg * 16 + ln;
                *(f32x4*)&st[row * 32 + ((quad ^ sw) * 4)]       = accA[rg] + bA;
                *(f32x4*)&st[row * 32 + (((4 + quad) ^ sw) * 4)] = accB[rg] + bB;
            }
            asm volatile("s_waitcnt lgkmcnt(0)" ::: "memory");
            #pragma unroll
            for (int rr = 0; rr < 4; ++rr) {
                const int rl = rr * 8 + (lane >> 3);
                const f32x4 v = *(const f32x4*)&st[rl * 32 + (((lane & 7) ^ (rl & 7)) * 4)];
                const int row = wv * 32 + rl;
                const int sd = row >> 6, ii = row & 63;
                __builtin_nontemporal_store(v,
                    (f32x4*)&out[(long)sd * side_stride + (rowbase + ii) * 128
                                 + p * 32 + (lane & 7) * 4]);
            }
        }
    }
}

extern "C" void kernel_launch(void* const* d_in, const int* in_sizes, int n_in,
                              void* d_out, int out_size, void* d_ws, size_t ws_size,
                              hipStream_t stream) {
    (void)in_sizes; (void)n_in; (void)out_size;
    const int*   src_ids = (const int*)  d_in[0];
    const int*   dst_ids = (const int*)  d_in[1];
    const int*   src_nid = (const int*)  d_in[2];
    const int*   dst_nid = (const int*)  d_in[3];
    const float* t_now   = (const float*)d_in[4];
    const float* src_t   = (const float*)d_in[5];
    const float* dst_t   = (const float*)d_in[6];
    const float* W1      = (const float*)d_in[7];
    const float* b1      = (const float*)d_in[8];
    const float* W2      = (const float*)d_in[9];
    const float* b2      = (const float*)d_in[10];
    float* out = (float*)d_out;

    const size_t FEAT_BYTES = 262144ULL * 8 * sizeof(float);   // 8.39 MB

    if (ws_size >= FEAT_BYTES) {
        float* fs = (float*)d_ws;
        lpe_feats<<<2048, 128, 0, stream>>>(src_ids, dst_ids, src_nid, dst_nid,
                                            t_now, src_t, dst_t, fs);
        lpe_gemm<<<1024, 256, 0, stream>>>(fs, W2, W1, b1, b2, out);
    } else {
        lpe_fused4<<<512, 256, 0, stream>>>(src_ids, dst_ids, src_nid, dst_nid,
                                            t_now, src_t, dst_t, W1, b1, W2, b2, out);
    }
}

// Round 7
// 193.642 us; speedup vs baseline: 1.1079x; 1.1079x over previous
//
#include <hip/hip_runtime.h>

// LocalPathEncoderRobustAdvancedTemporal — R10: R8 structure, subtractive-only.
// out[b,l,:] = (Σ_f relu(x_f*W1 + b1)) @ W2 + 8*b2   (8x FLOP collapse, exact)
//
// R9 (persistent grid=1024, 3 changes at once) regressed 185->215: exactly-
// filled persistent grid has zero cross-block slack; makespan = slowest CU.
// R10 reverts to the best-measured R8 split (2048-block k2, 3/CU) with only
// strictly-subtractive deltas:
//  * w2t_prep dispatch merged into k1 (blocks 0-63 also convert W2 -> bf16;
//    k2 launches after k1 drains, so no sync needed) -> one fewer dispatch.
//  * k2 epilogue: direct nt f32x4 stores. R5/R6 A/B proved store format is
//    neutral, so the LDS round trip + 8 wave-wide lgkmcnt fences per block
//    were pure overhead. -4KB LDS, fewer VGPRs, same store count.
//  * k1 stats/features + k2 staging/first-layer/MFMA: verbatim R8 (verified).

#define EPSF 1e-6f
#define LDB 136

typedef __attribute__((ext_vector_type(8))) short bf16x8;
typedef __attribute__((ext_vector_type(4))) float f32x4;
typedef __attribute__((ext_vector_type(2))) float f32x2;

__device__ inline short f2bf(float x) {           // fp32 -> bf16 (RNE)
    unsigned u = __float_as_uint(x);
    return (short)((u + 0x7fffu + ((u >> 16) & 1u)) >> 16);
}

// ------- k1: stats + cross features -> feats[2][2048][64][8]; W2 -> bf16 -------
__launch_bounds__(128)
__global__ void lpe_feats(const int* __restrict__ src_ids,
                          const int* __restrict__ dst_ids,
                          const int* __restrict__ src_nid,
                          const int* __restrict__ dst_nid,
                          const float* __restrict__ t_now,
                          const float* __restrict__ src_t,
                          const float* __restrict__ dst_t,
                          const float* __restrict__ W2,
                          float* __restrict__ fs,
                          short* __restrict__ w2t)
{
    __shared__ int2  s_idt[128];                  // (id, t) per local row
    __shared__ __align__(16) f32x4 s_tab[2][512]; // per (side,id): n,avg,rec,last_t

    const int tid  = threadIdx.x;                 // 0..127
    const int b    = blockIdx.x;                  // one sample per block
    const int side = tid >> 6;
    const int i    = tid & 63;

    // blocks 0-63 additionally convert W2 (f32 [k][n]) -> w2t (bf16 [n][k]).
    // k2 is a later dispatch on the same stream, so no intra-grid sync needed.
    if (b < 64) {
        #pragma unroll
        for (int u = 0; u < 2; ++u) {
            const int idx = b * 256 + u * 128 + tid;   // 64*256 = 16384
            const int k = idx >> 7, n = idx & 127;
            w2t[n * 128 + k] = f2bf(W2[idx]);
        }
    }

    // zero n-fields (other fields are n>0-guarded)
    #pragma unroll
    for (int u = tid; u < 1024; u += 128) ((float*)s_tab)[u * 4] = 0.f;

    const float cur = t_now[b];
    const int   s_n = src_nid[b], d_n = dst_nid[b];

    const int*   idp = side ? dst_ids : src_ids;
    const float* tp  = side ? dst_t   : src_t;
    const int   my_id = idp[b * 64 + i];
    const float my_t  = tp [b * 64 + i];
    s_idt[tid] = make_int2(my_id, __float_as_int(my_t));
    __syncthreads();

    // ---- stats: n, tmax, tmin, rank, has-later ----
    int n = 0, rank = 0, later = 0;
    float tmax = -3.4e38f, tmin = 3.4e38f;
    const int sbase = side * 64;
    #pragma unroll 8
    for (int j = 0; j < 64; ++j) {
        const int2 e = s_idt[sbase + j];
        const float tj = __int_as_float(e.y);
        if (e.x == my_id) {
            ++n;
            tmax = fmaxf(tmax, tj);
            tmin = fminf(tmin, tj);
            if (tj < my_t || (tj == my_t && j < i)) ++rank;
            if (j > i) later = 1;
        }
    }
    const float nf    = (float)n;
    const int   split = n >> 1;
    const float avg   = (n > 1) ? (tmax - tmin) / (nf - 1.f) : 0.f;
    if (my_id != 0) {
        s_tab[side][my_id].x = nf;     // benign race: same value from all members
        s_tab[side][my_id].y = avg;
        if (rank == split)             // unique member: sorted(ts)[n//2] == my_t
            s_tab[side][my_id].z = (n >= 4)
                ? (tmax - my_t) / fmaxf(nf - (float)split - 1.f, 1.f) : 0.f;
        if (!later)                    // unique member: last occurrence
            s_tab[side][my_id].w = my_t;
    }
    __syncthreads();

    // ---- cross features: O(1) table reads ----
    const int os = side ^ 1;
    const float rec_m = (my_id != 0) ? s_tab[side][my_id].z : 0.f;
    const f32x4 to = s_tab[os][my_id];
    const float n_o = (my_id != 0) ? to.x : 0.f;
    const bool  hit = n_o > 0.f;
    const float avg_o = hit ? to.y : 0.f;
    const float rec_o = hit ? to.z : 0.f;
    const float lastt = hit ? to.w : 0.f;
    const int other_node = side ? s_n : d_n;
    const float m = (my_id != 0) ? 1.f : 0.f;

    const float rcy_s = cur - my_t;
    const float rcy_o = cur - lastt;
    f32x4 f0, f1;
    f0.x = m * nf;
    f0.y = m * n_o;
    f0.z = m * ((my_id == other_node) ? 1.f : 0.f);
    f0.w = m * (hit ? 1.f : 0.f);
    f1.x = m * (hit ? nf / (n_o + EPSF) : 0.f);
    f1.y = m * ((rcy_s > EPSF) ? rcy_o / (rcy_s + EPSF) : 0.f);
    f1.z = m * ((avg_o > EPSF) ? avg / (avg_o + EPSF) : 0.f);
    f1.w = m * ((rec_o > EPSF) ? rec_m / (rec_o + EPSF) : 0.f);

    const long rowf = (long)side * 131072 + (long)b * 64 + i;   // [side][b][l]
    *(f32x4*)&fs[rowf * 8]     = f0;
    *(f32x4*)&fs[rowf * 8 + 4] = f1;
}

// ------- k2: streaming first-layer + GEMM + direct nt stores (R8 grid) -------
__launch_bounds__(256, 3)
__global__ void lpe_gemm(const float* __restrict__ fs,
                         const short* __restrict__ w2t,
                         const float* __restrict__ W1,
                         const float* __restrict__ b1,
                         const float* __restrict__ b2,
                         float* __restrict__ out)
{
    __shared__ __align__(16) float s_w1[128], s_b1[128], s_b2[128];
    __shared__ __align__(16) short W2T[128 * LDB];     // W2^T bf16, padded rows

    const int tid  = threadIdx.x;
    const int lane = tid & 63, wv = tid >> 6;
    const int quad = lane >> 4, ln = lane & 15;

    // stage W2^T (bf16, pre-converted) into padded LDS rows: 16B chunks
    #pragma unroll
    for (int it = 0; it < 8; ++it) {
        const int c = tid + it * 256;              // 2048 chunks of 8 shorts
        const int n = c >> 4, j = c & 15;
        *(bf16x8*)&W2T[n * LDB + j * 8] = *(const bf16x8*)&w2t[n * 128 + j * 8];
    }
    if (tid < 128) { s_w1[tid] = W1[tid]; s_b1[tid] = b1[tid]; s_b2[tid] = b2[tid]; }
    __syncthreads();

    const long base = (long)blockIdx.x * 128;      // 128 flat rows per block

    // ---- load feats for this wave's 32 rows ----
    float fxr[2][8];
    #pragma unroll
    for (int rg = 0; rg < 2; ++rg) {
        const long rowf = base + wv * 32 + rg * 16 + ln;
        const f32x4 a = *(const f32x4*)&fs[rowf * 8];
        const f32x4 c = *(const f32x4*)&fs[rowf * 8 + 4];
        fxr[rg][0] = a.x; fxr[rg][1] = a.y; fxr[rg][2] = a.z; fxr[rg][3] = a.w;
        fxr[rg][4] = c.x; fxr[rg][5] = c.y; fxr[rg][6] = c.z; fxr[rg][7] = c.w;
    }

    // ---- first layer: g = sum_f relu(x_f*W1+b1), bf16 fragments ----
    bf16x8 gf[2][4];                               // [row-tile][k-block]
    #pragma unroll
    for (int kk = 0; kk < 4; ++kk) {
        const int kb = kk * 32 + quad * 8;
        #pragma unroll
        for (int rg = 0; rg < 2; ++rg) {
            #pragma unroll
            for (int u2 = 0; u2 < 4; ++u2) {
                const f32x2 w  = *(const f32x2*)&s_w1[kb + u2 * 2];
                const f32x2 bb = *(const f32x2*)&s_b1[kb + u2 * 2];
                f32x2 sv = {0.f, 0.f};
                #pragma unroll
                for (int f = 0; f < 8; ++f) {
                    const f32x2 h = w * fxr[rg][f] + bb;      // v_pk_fma_f32
                    sv += __builtin_elementwise_max(h, (f32x2){0.f, 0.f});
                }
                gf[rg][kk][u2 * 2]     = f2bf(sv.x);
                gf[rg][kk][u2 * 2 + 1] = f2bf(sv.y);
            }
        }
    }

    // ---- GEMM + direct nt stores (format exonerated R5/R6; no fences) ----
    #pragma unroll
    for (int et = 0; et < 8; ++et) {
        bf16x8 af[4];
        #pragma unroll
        for (int kk = 0; kk < 4; ++kk)
            af[kk] = *(const bf16x8*)&W2T[(et * 16 + ln) * LDB + kk * 32 + quad * 8];
        f32x4 acc[2] = {(f32x4){0.f,0.f,0.f,0.f}, (f32x4){0.f,0.f,0.f,0.f}};
        #pragma unroll
        for (int kk = 0; kk < 4; ++kk)
            #pragma unroll
            for (int rg = 0; rg < 2; ++rg)
                acc[rg] = __builtin_amdgcn_mfma_f32_16x16x32_bf16(af[kk], gf[rg][kk], acc[rg], 0, 0, 0);

        const int e0 = et * 16 + quad * 4;
        const f32x4 badd = *(const f32x4*)&s_b2[e0] * 8.f;
        #pragma unroll
        for (int rg = 0; rg < 2; ++rg) {
            const long rowf = base + wv * 32 + rg * 16 + ln;
            __builtin_nontemporal_store(acc[rg] + badd,
                (f32x4*)&out[rowf * 128 + e0]);
        }
    }
}

// ---------------- fallback: fused (ws too small) ----------------
__launch_bounds__(256, 2)
__global__ void lpe_fused4(const int* __restrict__ src_ids,
                           const int* __restrict__ dst_ids,
                           const int* __restrict__ src_nid,
                           const int* __restrict__ dst_nid,
                           const float* __restrict__ t_now,
                           const float* __restrict__ src_t,
                           const float* __restrict__ dst_t,
                           const float* __restrict__ W1,
                           const float* __restrict__ b1,
                           const float* __restrict__ W2,
                           const float* __restrict__ b2,
                           float* __restrict__ out)
{
    __shared__ int2  s_idt[128];
    __shared__ __align__(16) f32x4 s_tab[2][512];
    __shared__ float s_feats[128][9];
    __shared__ __align__(16) float s_w1[128], s_b1[128], s_b2[128];
    __shared__ __align__(16) short W2T[128 * LDB];

    const int tid  = threadIdx.x;
    const int b4   = blockIdx.x * 4;
    const int lane = tid & 63, wv = tid >> 6;
    const int quad = lane >> 4, ln = lane & 15;
    const int side = (tid >> 6) & 1;
    const int i    = tid & 63;

    if (tid < 128) { s_w1[tid] = W1[tid]; s_b1[tid] = b1[tid]; s_b2[tid] = b2[tid]; }
    for (int u = tid; u < 16384; u += 256) {
        const int k = u >> 7, n = u & 127;
        W2T[n * LDB + k] = f2bf(W2[u]);
    }
    const int*   idp = side ? dst_ids : src_ids;
    const float* tp  = side ? dst_t   : src_t;
    int   pf_id = 0; float pf_t = 0.f;
    if (tid < 128) { pf_id = idp[b4 * 64 + i]; pf_t = tp[b4 * 64 + i]; }
    float cur = t_now[b4];
    int   s_n = src_nid[b4], d_n = dst_nid[b4];
    for (int u = tid; u < 1024; u += 256) ((float*)s_tab)[u * 4] = 0.f;
    const long side_stride = 2048L * 64L * 128L;

    for (int s = 0; s < 4; ++s) {
        const int   my_id = pf_id;  const float my_t = pf_t;
        const float curs  = cur;    const int sns = s_n, dns = d_n;
        if (tid < 128) s_idt[tid] = make_int2(my_id, __float_as_int(my_t));
        __syncthreads();

        float nf = 0.f, avg = 0.f;
        if (tid < 128) {
            int n = 0, rank = 0, later = 0;
            float tmax = -3.4e38f, tmin = 3.4e38f;
            const int sbase = side * 64;
            #pragma unroll 8
            for (int j = 0; j < 64; ++j) {
                const int2 e = s_idt[sbase + j];
                const float tj = __int_as_float(e.y);
                if (e.x == my_id) {
                    ++n; tmax = fmaxf(tmax, tj); tmin = fminf(tmin, tj);
                    if (tj < my_t || (tj == my_t && j < i)) ++rank;
                    if (j > i) later = 1;
                }
            }
            nf = (float)n;
            const int split = n >> 1;
            avg = (n > 1) ? (tmax - tmin) / (nf - 1.f) : 0.f;
            if (my_id != 0) {
                s_tab[side][my_id].x = nf;
                s_tab[side][my_id].y = avg;
                if (rank == split)
                    s_tab[side][my_id].z = (n >= 4)
                        ? (tmax - my_t) / fmaxf(nf - (float)split - 1.f, 1.f) : 0.f;
                if (!later) s_tab[side][my_id].w = my_t;
            }
        }
        if (s < 3) {
            if (tid < 128) {
                pf_id = idp[(b4 + s + 1) * 64 + i];
                pf_t  = tp [(b4 + s + 1) * 64 + i];
            }
            cur = t_now[b4 + s + 1];
            s_n = src_nid[b4 + s + 1];
            d_n = dst_nid[b4 + s + 1];
        }
        __syncthreads();

        if (tid < 128) {
            const int os = side ^ 1;
            const float rec_m = (my_id != 0) ? s_tab[side][my_id].z : 0.f;
            const f32x4 to = s_tab[os][my_id];
            const float n_o = (my_id != 0) ? to.x : 0.f;
            const bool  hit = n_o > 0.f;
            const float avg_o = hit ? to.y : 0.f;
            const float rec_o = hit ? to.z : 0.f;
            const float lastt = hit ? to.w : 0.f;
            const int other_node = side ? sns : dns;
            const float m = (my_id != 0) ? 1.f : 0.f;
            const float rcy_s = curs - my_t;
            const float rcy_o = curs - lastt;
            s_feats[tid][0] = m * nf;
            s_feats[tid][1] = m * n_o;
            s_feats[tid][2] = m * ((my_id == other_node) ? 1.f : 0.f);
            s_feats[tid][3] = m * (hit ? 1.f : 0.f);
            s_feats[tid][4] = m * (hit ? nf / (n_o + EPSF) : 0.f);
            s_feats[tid][5] = m * ((rcy_s > EPSF) ? rcy_o / (rcy_s + EPSF) : 0.f);
            s_feats[tid][6] = m * ((avg_o > EPSF) ? avg / (avg_o + EPSF) : 0.f);
            s_feats[tid][7] = m * ((rec_o > EPSF) ? rec_m / (rec_o + EPSF) : 0.f);
        }
        __syncthreads();

        float fxr[2][8];
        #pragma unroll
        for (int rg = 0; rg < 2; ++rg) {
            const int row = wv * 32 + rg * 16 + ln;
            #pragma unroll
            for (int j = 0; j < 8; ++j) fxr[rg][j] = s_feats[row][j];
        }
        if (s < 3)
            for (int u = tid; u < 1024; u += 256) ((float*)s_tab)[u * 4] = 0.f;

        bf16x8 gf[2][4];
        #pragma unroll
        for (int kk = 0; kk < 4; ++kk) {
            const int kb = kk * 32 + quad * 8;
            #pragma unroll
            for (int rg = 0; rg < 2; ++rg) {
                #pragma unroll
                for (int u2 = 0; u2 < 4; ++u2) {
                    const f32x2 w  = *(const f32x2*)&s_w1[kb + u2 * 2];
                    const f32x2 bb = *(const f32x2*)&s_b1[kb + u2 * 2];
                    f32x2 sv = {0.f, 0.f};
                    #pragma unroll
                    for (int f = 0; f < 8; ++f) {
                        const f32x2 h = w * fxr[rg][f] + bb;
                        sv += __builtin_elementwise_max(h, (f32x2){0.f, 0.f});
                    }
                    gf[rg][kk][u2 * 2]     = f2bf(sv.x);
                    gf[rg][kk][u2 * 2 + 1] = f2bf(sv.y);
                }
            }
        }

        const long rowbase = (long)(b4 + s) * 64;
        #pragma unroll
        for (int et = 0; et < 8; ++et) {
            bf16x8 af[4];
            #pragma unroll
            for (int kk = 0; kk < 4; ++kk)
                af[kk] = *(const bf16x8*)&W2T[(et * 16 + ln) * LDB + kk * 32 + quad * 8];
            f32x4 acc[2] = {(f32x4){0.f,0.f,0.f,0.f}, (f32x4){0.f,0.f,0.f,0.f}};
            #pragma unroll
            for (int kk = 0; kk < 4; ++kk)
                #pragma unroll
                for (int rg = 0; rg < 2; ++rg)
                    acc[rg] = __builtin_amdgcn_mfma_f32_16x16x32_bf16(af[kk], gf[rg][kk], acc[rg], 0, 0, 0);

            const int e0 = et * 16 + quad * 4;
            const f32x4 badd = *(const f32x4*)&s_b2[e0] * 8.f;
            #pragma unroll
            for (int rg = 0; rg < 2; ++rg) {
                const int row = wv * 32 + rg * 16 + ln;
                const int sd = row >> 6, ii = row & 63;
                __builtin_nontemporal_store(acc[rg] + badd,
                    (f32x4*)&out[(long)sd * side_stride + (rowbase + ii) * 128 + e0]);
            }
        }
    }
}

extern "C" void kernel_launch(void* const* d_in, const int* in_sizes, int n_in,
                              void* d_out, int out_size, void* d_ws, size_t ws_size,
                              hipStream_t stream) {
    (void)in_sizes; (void)n_in; (void)out_size;
    const int*   src_ids = (const int*)  d_in[0];
    const int*   dst_ids = (const int*)  d_in[1];
    const int*   src_nid = (const int*)  d_in[2];
    const int*   dst_nid = (const int*)  d_in[3];
    const float* t_now   = (const float*)d_in[4];
    const float* src_t   = (const float*)d_in[5];
    const float* dst_t   = (const float*)d_in[6];
    const float* W1      = (const float*)d_in[7];
    const float* b1      = (const float*)d_in[8];
    const float* W2      = (const float*)d_in[9];
    const float* b2      = (const float*)d_in[10];
    float* out = (float*)d_out;

    // ws layout: [0, 32KB) w2t bf16; [32KB, 32KB + 8.39MB) feats f32
    const size_t W2T_BYTES  = 128 * 128 * sizeof(short);
    const size_t FEAT_BYTES = 262144ULL * 8 * sizeof(float);

    if (ws_size >= W2T_BYTES + FEAT_BYTES) {
        short* w2t = (short*)d_ws;
        float* fs  = (float*)((char*)d_ws + W2T_BYTES);
        lpe_feats<<<2048, 128, 0, stream>>>(src_ids, dst_ids, src_nid, dst_nid,
                                            t_now, src_t, dst_t, W2, fs, w2t);
        lpe_gemm<<<2048, 256, 0, stream>>>(fs, w2t, W1, b1, b2, out);
    } else {
        lpe_fused4<<<512, 256, 0, stream>>>(src_ids, dst_ids, src_nid, dst_nid,
                                            t_now, src_t, dst_t, W1, b1, W2, b2, out);
    }
}

// Round 8
// 192.066 us; speedup vs baseline: 1.1170x; 1.0082x over previous
//
#include <hip/hip_runtime.h>

// LocalPathEncoderRobustAdvancedTemporal — R11: k2 without W2T LDS staging.
// out[b,l,:] = (Σ_f relu(x_f*W1 + b1)) @ W2 + 8*b2   (8x FLOP collapse, exact)
//
// R10 (R8-replica minus work) = 193.6 vs R8's 185.3 -> R8 was favorable noise;
// measured band for ALL structures since R1 is ~185-215. Last subtractive
// lever: every k2 block stages 34KB W2^T into LDS + barrier before its 64KB
// of stores (8 stage/barrier rounds per CU). w2t is bf16 in L2 (4MB total af
// read traffic chip-wide), so read af fragments straight from L2 instead:
//  * k2: NO W2T LDS stage (only 1.5KB w1/b1/b2), barrier kept only for those;
//    af = 16B global loads from w2t (L2-hot). LDS 36->1.5KB,
//    __launch_bounds__(256,4). Everything else verbatim R10.
//  * k1 (feats + merged W2->bf16 convert): verbatim R10.
// If this is null too, the window is harness-fixed + sustained-rate-limited
// and the next round declares the ceiling.

#define EPSF 1e-6f
#define LDB 136

typedef __attribute__((ext_vector_type(8))) short bf16x8;
typedef __attribute__((ext_vector_type(4))) float f32x4;
typedef __attribute__((ext_vector_type(2))) float f32x2;

__device__ inline short f2bf(float x) {           // fp32 -> bf16 (RNE)
    unsigned u = __float_as_uint(x);
    return (short)((u + 0x7fffu + ((u >> 16) & 1u)) >> 16);
}

// ------- k1: stats + cross features -> feats[2][2048][64][8]; W2 -> bf16 -------
__launch_bounds__(128)
__global__ void lpe_feats(const int* __restrict__ src_ids,
                          const int* __restrict__ dst_ids,
                          const int* __restrict__ src_nid,
                          const int* __restrict__ dst_nid,
                          const float* __restrict__ t_now,
                          const float* __restrict__ src_t,
                          const float* __restrict__ dst_t,
                          const float* __restrict__ W2,
                          float* __restrict__ fs,
                          short* __restrict__ w2t)
{
    __shared__ int2  s_idt[128];                  // (id, t) per local row
    __shared__ __align__(16) f32x4 s_tab[2][512]; // per (side,id): n,avg,rec,last_t

    const int tid  = threadIdx.x;                 // 0..127
    const int b    = blockIdx.x;                  // one sample per block
    const int side = tid >> 6;
    const int i    = tid & 63;

    // blocks 0-63 additionally convert W2 (f32 [k][n]) -> w2t (bf16 [n][k]).
    // k2 is a later dispatch on the same stream, so no intra-grid sync needed.
    if (b < 64) {
        #pragma unroll
        for (int u = 0; u < 2; ++u) {
            const int idx = b * 256 + u * 128 + tid;   // 64*256 = 16384
            const int k = idx >> 7, n = idx & 127;
            w2t[n * 128 + k] = f2bf(W2[idx]);
        }
    }

    // zero n-fields (other fields are n>0-guarded)
    #pragma unroll
    for (int u = tid; u < 1024; u += 128) ((float*)s_tab)[u * 4] = 0.f;

    const float cur = t_now[b];
    const int   s_n = src_nid[b], d_n = dst_nid[b];

    const int*   idp = side ? dst_ids : src_ids;
    const float* tp  = side ? dst_t   : src_t;
    const int   my_id = idp[b * 64 + i];
    const float my_t  = tp [b * 64 + i];
    s_idt[tid] = make_int2(my_id, __float_as_int(my_t));
    __syncthreads();

    // ---- stats: n, tmax, tmin, rank, has-later ----
    int n = 0, rank = 0, later = 0;
    float tmax = -3.4e38f, tmin = 3.4e38f;
    const int sbase = side * 64;
    #pragma unroll 8
    for (int j = 0; j < 64; ++j) {
        const int2 e = s_idt[sbase + j];
        const float tj = __int_as_float(e.y);
        if (e.x == my_id) {
            ++n;
            tmax = fmaxf(tmax, tj);
            tmin = fminf(tmin, tj);
            if (tj < my_t || (tj == my_t && j < i)) ++rank;
            if (j > i) later = 1;
        }
    }
    const float nf    = (float)n;
    const int   split = n >> 1;
    const float avg   = (n > 1) ? (tmax - tmin) / (nf - 1.f) : 0.f;
    if (my_id != 0) {
        s_tab[side][my_id].x = nf;     // benign race: same value from all members
        s_tab[side][my_id].y = avg;
        if (rank == split)             // unique member: sorted(ts)[n//2] == my_t
            s_tab[side][my_id].z = (n >= 4)
                ? (tmax - my_t) / fmaxf(nf - (float)split - 1.f, 1.f) : 0.f;
        if (!later)                    // unique member: last occurrence
            s_tab[side][my_id].w = my_t;
    }
    __syncthreads();

    // ---- cross features: O(1) table reads ----
    const int os = side ^ 1;
    const float rec_m = (my_id != 0) ? s_tab[side][my_id].z : 0.f;
    const f32x4 to = s_tab[os][my_id];
    const float n_o = (my_id != 0) ? to.x : 0.f;
    const bool  hit = n_o > 0.f;
    const float avg_o = hit ? to.y : 0.f;
    const float rec_o = hit ? to.z : 0.f;
    const float lastt = hit ? to.w : 0.f;
    const int other_node = side ? s_n : d_n;
    const float m = (my_id != 0) ? 1.f : 0.f;

    const float rcy_s = cur - my_t;
    const float rcy_o = cur - lastt;
    f32x4 f0, f1;
    f0.x = m * nf;
    f0.y = m * n_o;
    f0.z = m * ((my_id == other_node) ? 1.f : 0.f);
    f0.w = m * (hit ? 1.f : 0.f);
    f1.x = m * (hit ? nf / (n_o + EPSF) : 0.f);
    f1.y = m * ((rcy_s > EPSF) ? rcy_o / (rcy_s + EPSF) : 0.f);
    f1.z = m * ((avg_o > EPSF) ? avg / (avg_o + EPSF) : 0.f);
    f1.w = m * ((rec_o > EPSF) ? rec_m / (rec_o + EPSF) : 0.f);

    const long rowf = (long)side * 131072 + (long)b * 64 + i;   // [side][b][l]
    *(f32x4*)&fs[rowf * 8]     = f0;
    *(f32x4*)&fs[rowf * 8 + 4] = f1;
}

// ------- k2: streaming first-layer + GEMM; af straight from L2 (no W2T stage) -------
__launch_bounds__(256, 4)
__global__ void lpe_gemm(const float* __restrict__ fs,
                         const short* __restrict__ w2t,
                         const float* __restrict__ W1,
                         const float* __restrict__ b1,
                         const float* __restrict__ b2,
                         float* __restrict__ out)
{
    __shared__ __align__(16) float s_w1[128], s_b1[128], s_b2[128];

    const int tid  = threadIdx.x;
    const int lane = tid & 63, wv = tid >> 6;
    const int quad = lane >> 4, ln = lane & 15;

    const long base = (long)blockIdx.x * 128;      // 128 flat rows per block

    // ---- feats loads issued before the barrier (no LDS dependency) ----
    float fxr[2][8];
    #pragma unroll
    for (int rg = 0; rg < 2; ++rg) {
        const long rowf = base + wv * 32 + rg * 16 + ln;
        const f32x4 a = *(const f32x4*)&fs[rowf * 8];
        const f32x4 c = *(const f32x4*)&fs[rowf * 8 + 4];
        fxr[rg][0] = a.x; fxr[rg][1] = a.y; fxr[rg][2] = a.z; fxr[rg][3] = a.w;
        fxr[rg][4] = c.x; fxr[rg][5] = c.y; fxr[rg][6] = c.z; fxr[rg][7] = c.w;
    }

    if (tid < 128) { s_w1[tid] = W1[tid]; s_b1[tid] = b1[tid]; s_b2[tid] = b2[tid]; }
    __syncthreads();                               // only 1.5KB staged

    // ---- first layer: g = sum_f relu(x_f*W1+b1), bf16 fragments ----
    bf16x8 gf[2][4];                               // [row-tile][k-block]
    #pragma unroll
    for (int kk = 0; kk < 4; ++kk) {
        const int kb = kk * 32 + quad * 8;
        #pragma unroll
        for (int rg = 0; rg < 2; ++rg) {
            #pragma unroll
            for (int u2 = 0; u2 < 4; ++u2) {
                const f32x2 w  = *(const f32x2*)&s_w1[kb + u2 * 2];
                const f32x2 bb = *(const f32x2*)&s_b1[kb + u2 * 2];
                f32x2 sv = {0.f, 0.f};
                #pragma unroll
                for (int f = 0; f < 8; ++f) {
                    const f32x2 h = w * fxr[rg][f] + bb;      // v_pk_fma_f32
                    sv += __builtin_elementwise_max(h, (f32x2){0.f, 0.f});
                }
                gf[rg][kk][u2 * 2]     = f2bf(sv.x);
                gf[rg][kk][u2 * 2 + 1] = f2bf(sv.y);
            }
        }
    }

    // ---- GEMM: af fragments straight from L2-resident w2t; direct nt stores ----
    #pragma unroll
    for (int et = 0; et < 8; ++et) {
        bf16x8 af[4];
        #pragma unroll
        for (int kk = 0; kk < 4; ++kk)
            af[kk] = *(const bf16x8*)&w2t[(et * 16 + ln) * 128 + kk * 32 + quad * 8];
        f32x4 acc[2] = {(f32x4){0.f,0.f,0.f,0.f}, (f32x4){0.f,0.f,0.f,0.f}};
        #pragma unroll
        for (int kk = 0; kk < 4; ++kk)
            #pragma unroll
            for (int rg = 0; rg < 2; ++rg)
                acc[rg] = __builtin_amdgcn_mfma_f32_16x16x32_bf16(af[kk], gf[rg][kk], acc[rg], 0, 0, 0);

        const int e0 = et * 16 + quad * 4;
        const f32x4 badd = *(const f32x4*)&s_b2[e0] * 8.f;
        #pragma unroll
        for (int rg = 0; rg < 2; ++rg) {
            const long rowf = base + wv * 32 + rg * 16 + ln;
            __builtin_nontemporal_store(acc[rg] + badd,
                (f32x4*)&out[rowf * 128 + e0]);
        }
    }
}

// ---------------- fallback: fused (ws too small) ----------------
__launch_bounds__(256, 2)
__global__ void lpe_fused4(const int* __restrict__ src_ids,
                           const int* __restrict__ dst_ids,
                           const int* __restrict__ src_nid,
                           const int* __restrict__ dst_nid,
                           const float* __restrict__ t_now,
                           const float* __restrict__ src_t,
                           const float* __restrict__ dst_t,
                           const float* __restrict__ W1,
                           const float* __restrict__ b1,
                           const float* __restrict__ W2,
                           const float* __restrict__ b2,
                           float* __restrict__ out)
{
    __shared__ int2  s_idt[128];
    __shared__ __align__(16) f32x4 s_tab[2][512];
    __shared__ float s_feats[128][9];
    __shared__ __align__(16) float s_w1[128], s_b1[128], s_b2[128];
    __shared__ __align__(16) short W2T[128 * LDB];

    const int tid  = threadIdx.x;
    const int b4   = blockIdx.x * 4;
    const int lane = tid & 63, wv = tid >> 6;
    const int quad = lane >> 4, ln = lane & 15;
    const int side = (tid >> 6) & 1;
    const int i    = tid & 63;

    if (tid < 128) { s_w1[tid] = W1[tid]; s_b1[tid] = b1[tid]; s_b2[tid] = b2[tid]; }
    for (int u = tid; u < 16384; u += 256) {
        const int k = u >> 7, n = u & 127;
        W2T[n * LDB + k] = f2bf(W2[u]);
    }
    const int*   idp = side ? dst_ids : src_ids;
    const float* tp  = side ? dst_t   : src_t;
    int   pf_id = 0; float pf_t = 0.f;
    if (tid < 128) { pf_id = idp[b4 * 64 + i]; pf_t = tp[b4 * 64 + i]; }
    float cur = t_now[b4];
    int   s_n = src_nid[b4], d_n = dst_nid[b4];
    for (int u = tid; u < 1024; u += 256) ((float*)s_tab)[u * 4] = 0.f;
    const long side_stride = 2048L * 64L * 128L;

    for (int s = 0; s < 4; ++s) {
        const int   my_id = pf_id;  const float my_t = pf_t;
        const float curs  = cur;    const int sns = s_n, dns = d_n;
        if (tid < 128) s_idt[tid] = make_int2(my_id, __float_as_int(my_t));
        __syncthreads();

        float nf = 0.f, avg = 0.f;
        if (tid < 128) {
            int n = 0, rank = 0, later = 0;
            float tmax = -3.4e38f, tmin = 3.4e38f;
            const int sbase = side * 64;
            #pragma unroll 8
            for (int j = 0; j < 64; ++j) {
                const int2 e = s_idt[sbase + j];
                const float tj = __int_as_float(e.y);
                if (e.x == my_id) {
                    ++n; tmax = fmaxf(tmax, tj); tmin = fminf(tmin, tj);
                    if (tj < my_t || (tj == my_t && j < i)) ++rank;
                    if (j > i) later = 1;
                }
            }
            nf = (float)n;
            const int split = n >> 1;
            avg = (n > 1) ? (tmax - tmin) / (nf - 1.f) : 0.f;
            if (my_id != 0) {
                s_tab[side][my_id].x = nf;
                s_tab[side][my_id].y = avg;
                if (rank == split)
                    s_tab[side][my_id].z = (n >= 4)
                        ? (tmax - my_t) / fmaxf(nf - (float)split - 1.f, 1.f) : 0.f;
                if (!later) s_tab[side][my_id].w = my_t;
            }
        }
        if (s < 3) {
            if (tid < 128) {
                pf_id = idp[(b4 + s + 1) * 64 + i];
                pf_t  = tp [(b4 + s + 1) * 64 + i];
            }
            cur = t_now[b4 + s + 1];
            s_n = src_nid[b4 + s + 1];
            d_n = dst_nid[b4 + s + 1];
        }
        __syncthreads();

        if (tid < 128) {
            const int os = side ^ 1;
            const float rec_m = (my_id != 0) ? s_tab[side][my_id].z : 0.f;
            const f32x4 to = s_tab[os][my_id];
            const float n_o = (my_id != 0) ? to.x : 0.f;
            const bool  hit = n_o > 0.f;
            const float avg_o = hit ? to.y : 0.f;
            const float rec_o = hit ? to.z : 0.f;
            const float lastt = hit ? to.w : 0.f;
            const int other_node = side ? sns : dns;
            const float m = (my_id != 0) ? 1.f : 0.f;
            const float rcy_s = curs - my_t;
            const float rcy_o = curs - lastt;
            s_feats[tid][0] = m * nf;
            s_feats[tid][1] = m * n_o;
            s_feats[tid][2] = m * ((my_id == other_node) ? 1.f : 0.f);
            s_feats[tid][3] = m * (hit ? 1.f : 0.f);
            s_feats[tid][4] = m * (hit ? nf / (n_o + EPSF) : 0.f);
            s_feats[tid][5] = m * ((rcy_s > EPSF) ? rcy_o / (rcy_s + EPSF) : 0.f);
            s_feats[tid][6] = m * ((avg_o > EPSF) ? avg / (avg_o + EPSF) : 0.f);
            s_feats[tid][7] = m * ((rec_o > EPSF) ? rec_m / (rec_o + EPSF) : 0.f);
        }
        __syncthreads();

        float fxr[2][8];
        #pragma unroll
        for (int rg = 0; rg < 2; ++rg) {
            const int row = wv * 32 + rg * 16 + ln;
            #pragma unroll
            for (int j = 0; j < 8; ++j) fxr[rg][j] = s_feats[row][j];
        }
        if (s < 3)
            for (int u = tid; u < 1024; u += 256) ((float*)s_tab)[u * 4] = 0.f;

        bf16x8 gf[2][4];
        #pragma unroll
        for (int kk = 0; kk < 4; ++kk) {
            const int kb = kk * 32 + quad * 8;
            #pragma unroll
            for (int rg = 0; rg < 2; ++rg) {
                #pragma unroll
                for (int u2 = 0; u2 < 4; ++u2) {
                    const f32x2 w  = *(const f32x2*)&s_w1[kb + u2 * 2];
                    const f32x2 bb = *(const f32x2*)&s_b1[kb + u2 * 2];
                    f32x2 sv = {0.f, 0.f};
                    #pragma unroll
                    for (int f = 0; f < 8; ++f) {
                        const f32x2 h = w * fxr[rg][f] + bb;
                        sv += __builtin_elementwise_max(h, (f32x2){0.f, 0.f});
                    }
                    gf[rg][kk][u2 * 2]     = f2bf(sv.x);
                    gf[rg][kk][u2 * 2 + 1] = f2bf(sv.y);
                }
            }
        }

        const long rowbase = (long)(b4 + s) * 64;
        #pragma unroll
        for (int et = 0; et < 8; ++et) {
            bf16x8 af[4];
            #pragma unroll
            for (int kk = 0; kk < 4; ++kk)
                af[kk] = *(const bf16x8*)&W2T[(et * 16 + ln) * LDB + kk * 32 + quad * 8];
            f32x4 acc[2] = {(f32x4){0.f,0.f,0.f,0.f}, (f32x4){0.f,0.f,0.f,0.f}};
            #pragma unroll
            for (int kk = 0; kk < 4; ++kk)
                #pragma unroll
                for (int rg = 0; rg < 2; ++rg)
                    acc[rg] = __builtin_amdgcn_mfma_f32_16x16x32_bf16(af[kk], gf[rg][kk], acc[rg], 0, 0, 0);

            const int e0 = et * 16 + quad * 4;
            const f32x4 badd = *(const f32x4*)&s_b2[e0] * 8.f;
            #pragma unroll
            for (int rg = 0; rg < 2; ++rg) {
                const int row = wv * 32 + rg * 16 + ln;
                const int sd = row >> 6, ii = row & 63;
                __builtin_nontemporal_store(acc[rg] + badd,
                    (f32x4*)&out[(long)sd * side_stride + (rowbase + ii) * 128 + e0]);
            }
        }
    }
}

extern "C" void kernel_launch(void* const* d_in, const int* in_sizes, int n_in,
                              void* d_out, int out_size, void* d_ws, size_t ws_size,
                              hipStream_t stream) {
    (void)in_sizes; (void)n_in; (void)out_size;
    const int*   src_ids = (const int*)  d_in[0];
    const int*   dst_ids = (const int*)  d_in[1];
    const int*   src_nid = (const int*)  d_in[2];
    const int*   dst_nid = (const int*)  d_in[3];
    const float* t_now   = (const float*)d_in[4];
    const float* src_t   = (const float*)d_in[5];
    const float* dst_t   = (const float*)d_in[6];
    const float* W1      = (const float*)d_in[7];
    const float* b1      = (const float*)d_in[8];
    const float* W2      = (const float*)d_in[9];
    const float* b2      = (const float*)d_in[10];
    float* out = (float*)d_out;

    // ws layout: [0, 32KB) w2t bf16; [32KB, 32KB + 8.39MB) feats f32
    const size_t W2T_BYTES  = 128 * 128 * sizeof(short);
    const size_t FEAT_BYTES = 262144ULL * 8 * sizeof(float);

    if (ws_size >= W2T_BYTES + FEAT_BYTES) {
        short* w2t = (short*)d_ws;
        float* fs  = (float*)((char*)d_ws + W2T_BYTES);
        lpe_feats<<<2048, 128, 0, stream>>>(src_ids, dst_ids, src_nid, dst_nid,
                                            t_now, src_t, dst_t, W2, fs, w2t);
        lpe_gemm<<<2048, 256, 0, stream>>>(fs, w2t, W1, b1, b2, out);
    } else {
        lpe_fused4<<<512, 256, 0, stream>>>(src_ids, dst_ids, src_nid, dst_nid,
                                            t_now, src_t, dst_t, W1, b1, W2, b2, out);
    }
}